// Round 1
// 526.635 us; speedup vs baseline: 1.0575x; 1.0575x over previous
//
#include <hip/hip_runtime.h>

// RBM CD-1 step on MI355X — round 9.
// Main GEMM loop (256x256 tile, BK=32, 8 waves, depth-4 counted vmcnt(8)
// pipeline) is UNCHANGED from the verified round-8 kernel. This round attacks
// the serial epilogue bursts identified in rocprof (G4 = 142us at 19% MfmaUtil;
// uni/aux HBM reads fully exposed after compute):
//  - MODE 2/4: L2/L3 prefetch of the epilogue's uni/aux tile during the last
//    8 K-tiles (1 scalar load/thread/tile, asm-sunk; 64 distinct lines per
//    wave-instr). Extra outstanding VMEM only strengthens the counted
//    vmcnt(8) waits (prefetches are newest), so staging stays race-free.
//  - MODE 2/4 epilogue: two-phase, software-pipelined: issue 8 chunk loads ->
//    sigmoid all 128 accs in place (hides latency) -> depth-8 rolling window
//    consume (static indices only).
//  - MODE 4: vk now written coalesced (u16x8) from the ebuf instead of 128
//    scalar u16 stores per thread.
//  - Fast sigmoid 1/(1+__expf(-x)) everywhere (perturbation ~1e-6 rel,
//    negligible vs existing bf16 pre-activation noise).

typedef unsigned short u16;
typedef short s16x8 __attribute__((ext_vector_type(8)));
typedef float f32x4 __attribute__((ext_vector_type(4)));
typedef u16 u16x4 __attribute__((ext_vector_type(4)));
typedef u16 u16x8 __attribute__((ext_vector_type(8)));

constexpr int Bn = 8192, Vn = 2048, Hn = 1024;
constexpr size_t VH = (size_t)Vn * Hn;
constexpr size_t BH = (size_t)Bn * Hn;
constexpr size_t OUT_RECON = BH;                        // 8388608
constexpr size_t OUT_WGRAD = OUT_RECON + 1;             // 8388609
constexpr size_t OUT_VBG   = OUT_WGRAD + VH;            // 10485761
constexpr size_t OUT_HBG   = OUT_VBG + Vn;              // 10487809

__device__ __forceinline__ u16 f2bf(float x) {
  union { float f; unsigned u; } a; a.f = x;
  unsigned r = a.u + 0x7FFFu + ((a.u >> 16) & 1u);   // RNE
  return (u16)(r >> 16);
}
__device__ __forceinline__ float bf2f(u16 h) {
  union { unsigned u; float f; } a; a.u = ((unsigned)h) << 16;
  return a.f;
}
__device__ __forceinline__ float sigmoidf_(float x) {
  return 1.0f / (1.0f + __expf(-x));
}

using gptr_t = const unsigned int __attribute__((address_space(1)))*;
using lptr_t = unsigned int __attribute__((address_space(3)))*;

__device__ __forceinline__ void gload16(const u16* g, u16* l) {
  __builtin_amdgcn_global_load_lds((gptr_t)(unsigned long long)g,
                                   (lptr_t)(unsigned long long)l, 16, 0, 0);
}

// ---------------- prep kernels ----------------

// v[B,V] f32 -> v_cat[B,2V]=[hi|lo], vT[V,B] (hi, transposed), vbd partials.
__global__ void prep_vt_k(const float* __restrict__ v, u16* __restrict__ vcat,
                          u16* __restrict__ vT, float* __restrict__ vbd_p) {
  __shared__ u16 tile[64][68];
  __shared__ float cs[16][64];
  const int b0 = blockIdx.x * 64, c0 = blockIdx.y * 64;
  const int t = threadIdx.x;
  const int rg = t >> 4;          // 0..15 row group
  const int cg = (t & 15) << 2;   // col *4
  float ca[4] = {0.f, 0.f, 0.f, 0.f};
#pragma unroll
  for (int i = 0; i < 4; ++i) {
    int r = rg + 16 * i;
    f32x4 x = *(const f32x4*)&v[(size_t)(b0 + r) * Vn + c0 + cg];
    u16x4 hi, lo;
#pragma unroll
    for (int j = 0; j < 4; ++j) {
      hi[j] = f2bf(x[j]);
      lo[j] = f2bf(x[j] - bf2f(hi[j]));
      tile[r][cg + j] = hi[j];
      ca[j] += x[j];
    }
    *(u16x4*)&vcat[(size_t)(b0 + r) * (2 * Vn) + c0 + cg] = hi;
    *(u16x4*)&vcat[(size_t)(b0 + r) * (2 * Vn) + Vn + c0 + cg] = lo;
  }
#pragma unroll
  for (int j = 0; j < 4; ++j) cs[rg][cg + j] = ca[j];
  __syncthreads();
  if (t < 64) {
    float s = 0.f;
#pragma unroll
    for (int k = 0; k < 16; ++k) s += cs[k][t];
    vbd_p[(size_t)blockIdx.x * Vn + c0 + t] = s;   // [128][2048]
  }
#pragma unroll
  for (int s2 = 0; s2 < 2; ++s2) {
    int c = t >> 2;
    int seg = (t & 3) + 4 * s2;
    u16x8 pk;
#pragma unroll
    for (int i = 0; i < 8; ++i) pk[i] = tile[seg * 8 + i][c];
    *(u16x8*)&vT[(size_t)(c0 + c) * Bn + b0 + seg * 8] = pk;
  }
}

// w[V,H] f32 -> w_cat[V,2H]=[hi|lo] and wT_cat[H,2V]=[hi|lo] (transposed)
__global__ void prep_w_k(const float* __restrict__ w, u16* __restrict__ w_cat,
                         u16* __restrict__ wTc) {
  __shared__ float tile[64][65];
  int v0 = blockIdx.x * 64, h0 = blockIdx.y * 64;
  int t = threadIdx.x, c = t & 63, r = t >> 6;
  for (int rr = r; rr < 64; rr += 4) {
    float x = w[(size_t)(v0 + rr) * Hn + h0 + c];
    tile[rr][c] = x;
    u16 hi = f2bf(x), lo = f2bf(x - bf2f(hi));
    w_cat[(size_t)(v0 + rr) * (2 * Hn) + h0 + c]      = hi;
    w_cat[(size_t)(v0 + rr) * (2 * Hn) + Hn + h0 + c] = lo;
  }
  __syncthreads();
  for (int rr = r; rr < 64; rr += 4) {
    float x = tile[c][rr];  // = w[v0+c][h0+rr]
    u16 hi = f2bf(x), lo = f2bf(x - bf2f(hi));
    size_t ro = (size_t)(h0 + rr) * (2 * Vn);
    wTc[ro + v0 + c]      = hi;
    wTc[ro + Vn + v0 + c] = lo;
  }
}

// ---- sampling epilogue for split-K [B,H] pre-activations ----------------
template <int M>
__global__ void epi_h_k(const float* __restrict__ p0, const float* __restrict__ p1,
                        const float* __restrict__ bias, const float* __restrict__ uni,
                        float* __restrict__ f32out, u16* __restrict__ hp_out,
                        u16* __restrict__ hbin_out, u16* __restrict__ tout,
                        float* __restrict__ colp) {
  __shared__ u16 tile[64][68];
  __shared__ float cs[16][64];
  const int b0 = blockIdx.x * 64, c0 = blockIdx.y * 64;
  const int t = threadIdx.x;
  const int rg = t >> 4, cg = (t & 15) << 2;
  float ca[4] = {0.f, 0.f, 0.f, 0.f};
#pragma unroll
  for (int i = 0; i < 4; ++i) {
    int r = rg + 16 * i;
    size_t e = (size_t)(b0 + r) * Hn + c0 + cg;
    f32x4 a = *(const f32x4*)&p0[e];
    f32x4 b = *(const f32x4*)&p1[e];
    f32x4 uu = *(const f32x4*)&uni[e];
    f32x4 hpv;
    u16x4 hb16, qv;
#pragma unroll
    for (int j = 0; j < 4; ++j) {
      float hp = sigmoidf_(a[j] + b[j] + bias[c0 + cg + j]);
      u16 qb = (hp > uu[j]) ? (u16)0x3F80 : (u16)0;
      tile[r][cg + j] = qb;
      if constexpr (M == 1) {
        hpv[j] = hp; hb16[j] = f2bf(hp); qv[j] = qb;
        ca[j] += hp;
      } else {
        ca[j] += (qb ? 1.f : 0.f);
      }
    }
    if constexpr (M == 1) {
      *(f32x4*)&f32out[e] = hpv;        // h_prediction (overwrites p0 region)
      *(u16x4*)&hp_out[e] = hb16;
      *(u16x4*)&hbin_out[e] = qv;
    }
  }
#pragma unroll
  for (int j = 0; j < 4; ++j) cs[rg][cg + j] = ca[j];
  __syncthreads();
  if (t < 64) {
    float s = 0.f;
#pragma unroll
    for (int k = 0; k < 16; ++k) s += cs[k][t];
    colp[(size_t)blockIdx.x * Hn + c0 + t] = s;   // [128][1024]
  }
#pragma unroll
  for (int s2 = 0; s2 < 2; ++s2) {
    int c = t >> 2;
    int seg = (t & 3) + 4 * s2;
    u16x8 pk;
#pragma unroll
    for (int i = 0; i < 8; ++i) pk[i] = tile[seg * 8 + i][c];
    *(u16x8*)&tout[(size_t)(c0 + c) * Bn + b0 + seg * 8] = pk;
  }
}

// ---------------- GEMM 256x256, BK=32, 8 waves, depth-4 counted pipeline --
// MODE 1: G1 split-K x2 partial (A remap [hi|hi|lo], B remap [hi|lo|hi]).
// MODE 2: G2 recon: A=h_p, B=w_cat hi, K=1024 -> recon partials (redp), aux=v.
// MODE 3: split-K x8 grad: A,B += z*K cols -> (z<4?f32out:redp)+(z&3)*VH.
// MODE 4: G4 vk: A=hbin (dup), B=w_cat, K=2048 -> vk, vkT, vbm (fused).
// MODE 5: G5 split-K x2 partial: A=vk (dup), B=wT_cat.
template <int MODE>
__global__ __launch_bounds__(512) void gemm256(
    const u16* __restrict__ A, int lda, const u16* __restrict__ Bm, int ldb, int K,
    const float* __restrict__ bias, const float* __restrict__ uni,
    const float* __restrict__ aux, float* __restrict__ f32out,
    u16* __restrict__ bfout, u16* __restrict__ bfout2,
    float* __restrict__ redp, u16* __restrict__ tout, float* __restrict__ colp) {
  constexpr bool TRANS = (MODE == 4);
  // As[4][256][32] at 0 (32768 u16), Bs[4][256][32] at 32768; 128 KB.
  // MODE4 epilogue ebuf [256][264] (67584 u16 = 132 KB) aliases everything.
  __shared__ __align__(16) u16 smem[TRANS ? 67584 : 65536];
  const int t = threadIdx.x;
  const int lane = t & 63, wave = t >> 6;                // 8 waves
  const int wr = (wave >> 2) << 7;                       // 0 / 128
  const int wc = (wave & 3) << 6;                        // 0/64/128/192
  const int bm = blockIdx.x << 8, bn = blockIdx.y << 8;
  int kbeg = 0;
  float* pout = f32out;
  if constexpr (MODE == 1 || MODE == 5) {
    kbeg = blockIdx.z * K;
    pout = (blockIdx.z == 0) ? f32out : redp;
  }
  if constexpr (MODE == 3) {
    size_t off = (size_t)blockIdx.z * (size_t)K;
    A += off;
    Bm += off;
    pout = ((blockIdx.z < 4) ? f32out : redp) + (size_t)(blockIdx.z & 3) * VH;
  }
  f32x4 acc[8][4] = {};
  // staging (one gload = 512 thr x 16B = 128 rows x 64B): LDS row sr = t>>2,
  // granule t&3; fetch SWIZZLED global granule (t&3) ^ ((row>>1)&3) [r5 T2].
  const int sr = t >> 2;
  const int sc = (((t & 3) ^ ((t >> 3) & 3)) << 3);
  const u16* Ag  = A  + (size_t)(bm + sr) * lda + sc;
  const u16* Ag2 = Ag + (size_t)128 * lda;
  const u16* Bg  = Bm + (size_t)(bn + sr) * ldb + sc;
  const u16* Bg2 = Bg + (size_t)128 * ldb;
  const int fr = lane & 15, fg = lane >> 4;
  const int ga = ((fg ^ ((fr >> 1) & 3)) << 3);          // swizzled read granule

  auto stage = [&](int kt) {
    const int k0 = kbeg + (kt << 5);
    int acol, bcol;
    if constexpr (MODE == 1) {
      acol = (k0 < 2048) ? k0 : k0 - 2048;               // [hi|hi|lo]
      bcol = (k0 < 4096) ? k0 : k0 - 4096;               // [hi|lo|hi]
    } else if constexpr (MODE == 4) { acol = k0 & 1023; bcol = k0; }
    else if constexpr (MODE == 5)   { acol = k0 & 2047; bcol = k0; }
    else                            { acol = k0;        bcol = k0; }
    const int pb = kt & 3;
    u16* ad = smem + pb * 8192 + wave * 512;             // wave-uniform base
    u16* bd = smem + 32768 + pb * 8192 + wave * 512;
    gload16(Ag + acol, ad);
    gload16(Ag2 + acol, ad + 4096);
    gload16(Bg + bcol, bd);
    gload16(Bg2 + bcol, bd + 4096);
  };
  auto compute = [&](int kt) {
    const int pb = kt & 3;
    const u16* Ab = smem + pb * 8192;
    const u16* Bb = smem + 32768 + pb * 8192;
    s16x8 bf[4], af[4];
#pragma unroll
    for (int n = 0; n < 4; ++n)
      bf[n] = *(const s16x8*)&Bb[(wc + n * 16 + fr) * 32 + ga];
#pragma unroll
    for (int m = 0; m < 4; ++m)
      af[m] = *(const s16x8*)&Ab[(wr + m * 16 + fr) * 32 + ga];
    __builtin_amdgcn_s_setprio(1);
#pragma unroll
    for (int m = 0; m < 4; ++m)
#pragma unroll
      for (int n = 0; n < 4; ++n)
        acc[m][n] = __builtin_amdgcn_mfma_f32_16x16x32_bf16(af[m], bf[n], acc[m][n], 0, 0, 0);
    __builtin_amdgcn_s_setprio(0);
#pragma unroll
    for (int m = 0; m < 4; ++m)
      af[m] = *(const s16x8*)&Ab[(wr + (m + 4) * 16 + fr) * 32 + ga];
    __builtin_amdgcn_s_setprio(1);
#pragma unroll
    for (int m = 0; m < 4; ++m)
#pragma unroll
      for (int n = 0; n < 4; ++n)
        acc[m + 4][n] = __builtin_amdgcn_mfma_f32_16x16x32_bf16(af[m], bf[n], acc[m + 4][n], 0, 0, 0);
    __builtin_amdgcn_s_setprio(0);
  };

  // depth-4 pipeline: stage T+3 each iter; vmcnt(8) waits own tile-T loads
  // (12 outstanding -> 8); barrier publishes all waves' slices.
  const int NT = K >> 5;               // >= 32 for all modes
  stage(0); stage(1); stage(2);
  int T = 0;
  for (; T < NT - 3; ++T) {
    asm volatile("s_waitcnt vmcnt(8)" ::: "memory");
    __builtin_amdgcn_s_barrier();
    asm volatile("" ::: "memory");
    stage(T + 3);
    if constexpr (MODE == 2 || MODE == 4) {
      // L2/L3 prefetch of the epilogue's uni/aux tile over the last 8 tiles.
      // 1 scalar f32/lane -> each wave-instr touches 64 distinct 64B lines.
      // Prefetches are NEWER than all staging loads they coexist with, so the
      // counted vmcnt(8) waits only get stronger (forces more of the oldest
      // staging loads to complete) -> race-free.
      const int pfbeg = NT - 11;
      if (T >= pfbeg) {
        const float* pfp = (MODE == 2) ? aux : uni;
        const int L = ((T - pfbeg) << 9) + t;            // 0..4095
        float pf = pfp[(size_t)(bm + (L >> 4)) * Vn + bn + ((L & 15) << 4)];
        asm volatile("" :: "v"(pf));
      }
    }
    compute(T);
  }
  asm volatile("s_waitcnt vmcnt(8)" ::: "memory");
  __builtin_amdgcn_s_barrier();
  asm volatile("" ::: "memory");
  compute(T++);
  asm volatile("s_waitcnt vmcnt(4)" ::: "memory");
  __builtin_amdgcn_s_barrier();
  asm volatile("" ::: "memory");
  compute(T++);
  asm volatile("s_waitcnt vmcnt(0)" ::: "memory");
  __builtin_amdgcn_s_barrier();
  asm volatile("" ::: "memory");
  compute(T);

  // ---- epilogue ----
  constexpr int NC = (MODE == 2 || MODE == 4) ? Vn : Hn;
  const int fq = lane >> 4;

  if constexpr (MODE == 1 || MODE == 3 || MODE == 5) {
#pragma unroll
    for (int m = 0; m < 8; ++m)
#pragma unroll
      for (int n = 0; n < 4; ++n)
#pragma unroll
        for (int j = 0; j < 4; ++j) {
          int rl = wr + m * 16 + fq * 4 + j;
          int cl = wc + n * 16 + fr;
          pout[(size_t)(bm + rl) * NC + bn + cl] = acc[m][n][j];
        }
  }

  if constexpr (MODE == 2) {
    // two-phase pipelined recon: issue 8 chunk loads -> sigmoid in place
    // (hides latency; uni tile is L2-warm from the main-loop prefetch) ->
    // depth-8 rolling-window consume. Static indices only (ax[ci&7]).
    float bcol[4];
#pragma unroll
    for (int n = 0; n < 4; ++n) bcol[n] = bias[bn + wc + n * 16 + fr];
    const size_t ebase = (size_t)(bm + wr + fq * 4) * NC + (bn + wc + fr);
    float ax[8][4];
    auto ld4 = [&](int ci, float* dst) {
      size_t e0 = ebase + (size_t)((ci >> 2) << 4) * NC + ((ci & 3) << 4);
      dst[0] = aux[e0];          dst[1] = aux[e0 + NC];
      dst[2] = aux[e0 + 2 * NC]; dst[3] = aux[e0 + 3 * NC];
    };
#pragma unroll
    for (int ci = 0; ci < 8; ++ci) ld4(ci, ax[ci]);
#pragma unroll
    for (int m = 0; m < 8; ++m)
#pragma unroll
      for (int n = 0; n < 4; ++n)
#pragma unroll
        for (int j = 0; j < 4; ++j)
          acc[m][n][j] = sigmoidf_(acc[m][n][j] + bcol[n]);
    float lsum = 0.f;
#pragma unroll
    for (int ci = 0; ci < 32; ++ci) {
      const int m = ci >> 2, n = ci & 3;
#pragma unroll
      for (int j = 0; j < 4; ++j) lsum += fabsf(ax[ci & 7][j] - acc[m][n][j]);
      if (ci < 24) ld4(ci + 8, ax[ci & 7]);
    }
#pragma unroll
    for (int off = 32; off > 0; off >>= 1) lsum += __shfl_down(lsum, off);
    __syncthreads();
    float* redlds = (float*)smem;
    if (lane == 0) redlds[wave] = lsum;
    __syncthreads();
    if (t == 0) {
      float s = 0.f;
#pragma unroll
      for (int wv = 0; wv < 8; ++wv) s += redlds[wv];
      redp[(size_t)blockIdx.y * gridDim.x + blockIdx.x] = s;
    }
  }

  if constexpr (MODE == 4) {
    __syncthreads();   // all waves done with dbuf before ebuf writes
    float bcol[4];
#pragma unroll
    for (int n = 0; n < 4; ++n) bcol[n] = bias[bn + wc + n * 16 + fr];
    const size_t ebase = (size_t)(bm + wr + fq * 4) * NC + (bn + wc + fr);
    float ux[8][4];
    auto ld4 = [&](int ci, float* dst) {
      size_t e0 = ebase + (size_t)((ci >> 2) << 4) * NC + ((ci & 3) << 4);
      dst[0] = uni[e0];          dst[1] = uni[e0 + NC];
      dst[2] = uni[e0 + 2 * NC]; dst[3] = uni[e0 + 3 * NC];
    };
#pragma unroll
    for (int ci = 0; ci < 8; ++ci) ld4(ci, ux[ci]);
#pragma unroll
    for (int m = 0; m < 8; ++m)
#pragma unroll
      for (int n = 0; n < 4; ++n)
#pragma unroll
        for (int j = 0; j < 4; ++j)
          acc[m][n][j] = sigmoidf_(acc[m][n][j] + bcol[n]);
    float csum[4] = {0.f, 0.f, 0.f, 0.f};
#pragma unroll
    for (int ci = 0; ci < 32; ++ci) {
      const int m = ci >> 2, n = ci & 3;
      const int rl = wr + m * 16 + fq * 4;
      const int cl = wc + n * 16 + fr;
#pragma unroll
      for (int j = 0; j < 4; ++j) {
        u16 qb = (acc[m][n][j] > ux[ci & 7][j]) ? (u16)0x3F80 : (u16)0;
        smem[(rl + j) * 264 + cl] = qb;          // ebuf (feeds vk AND vkT)
        csum[n] += (qb ? 1.f : 0.f);
      }
      if (ci < 24) ld4(ci + 8, ux[ci & 7]);
    }
    // vbm partials: lane covers 32 rows; xor16+xor32 reduces fq -> 128 rows
#pragma unroll
    for (int n = 0; n < 4; ++n) {
      float s = csum[n];
      s += __shfl_xor(s, 16);
      s += __shfl_xor(s, 32);
      if (fq == 0)
        colp[(size_t)(blockIdx.x * 2 + (wr >> 7)) * NC + (bn + wc + n * 16 + fr)] = s;
    }
    __syncthreads();   // ebuf fully written
    // vk row-major writeout: coalesced u16x8 from ebuf (replaces 128 scalar
    // global stores/thread). 256 rows x 32 col-chunks = 8192 tasks / 512 thr.
#pragma unroll
    for (int it = 0; it < 16; ++it) {
      int id = t + (it << 9);
      int r = id >> 5;                   // 0..255
      int c0 = (id & 31) << 3;           // 0..248
      u16x8 pk = *(const u16x8*)&smem[r * 264 + c0];
      *(u16x8*)&bfout[(size_t)(bm + r) * NC + bn + c0] = pk;
    }
    // transposed write-out: 256 cols x 32 row-groups(8) = 8192 tasks / 512 thr
#pragma unroll
    for (int it = 0; it < 16; ++it) {
      int id = t + (it << 9);
      int c = id & 255;
      int rg2 = id >> 8;                 // 0..31
      u16x8 pk;
#pragma unroll
      for (int i2 = 0; i2 < 8; ++i2) pk[i2] = smem[(rg2 * 8 + i2) * 264 + c];
      *(u16x8*)&tout[(size_t)(bn + c) * Bn + bm + rg2 * 8] = pk;
    }
  }
}

// out[i] = sum_{z<8} p[z][i]  (scalar stores: out base misaligned)
__global__ void reduce8_k(const float* __restrict__ p, float* __restrict__ out) {
  size_t e = ((size_t)blockIdx.x * 256 + threadIdx.x) * 4;
  f32x4 r = {};
#pragma unroll
  for (int z = 0; z < 8; ++z) r += *(const f32x4*)&p[(size_t)z * VH + e];
  out[e + 0] = r[0]; out[e + 1] = r[1]; out[e + 2] = r[2]; out[e + 3] = r[3];
}

// out[i] = sum_{z<4} pa[z][i] + sum_{z<4} pb[z][i] - sub[i]   (w_grad final)
__global__ void reduce8s_k(const float* __restrict__ pa, const float* __restrict__ pb,
                           const float* __restrict__ sub, float* __restrict__ out) {
  size_t e = ((size_t)blockIdx.x * 256 + threadIdx.x) * 4;
  f32x4 r = {};
#pragma unroll
  for (int z = 0; z < 4; ++z) r += *(const f32x4*)&pa[(size_t)z * VH + e];
#pragma unroll
  for (int z = 0; z < 4; ++z) r += *(const f32x4*)&pb[(size_t)z * VH + e];
  float s0 = sub[e + 0], s1 = sub[e + 1], s2 = sub[e + 2], s3 = sub[e + 3];
  out[e + 0] = r[0] - s0; out[e + 1] = r[1] - s1;
  out[e + 2] = r[2] - s2; out[e + 3] = r[3] - s3;
}

// final reductions: bias grads + recon scalar
// vbd:128 part., hbd:128, vbm:64, hbm:128, recon:256
__global__ void finalize_k(const float* __restrict__ sums, float* __restrict__ out) {
  int i = blockIdx.x * 256 + threadIdx.x;
  const float* recon_p = sums;                 // 256
  const float* vbd = sums + 1024;              // 128 x 2048
  const float* hbd = vbd + 128 * 2048;         // 128 x 1024
  const float* vbm = hbd + 128 * 1024;         // 64 x 2048
  const float* hbm = vbm + 128 * 2048;         // 128 x 1024
  if (i < 2048) {
    float d = 0.f, m = 0.f;
    for (int k = 0; k < 128; ++k) d += vbd[k * 2048 + i];
    for (int k = 0; k < 64; ++k)  m += vbm[k * 2048 + i];
    out[OUT_VBG + i] = m - d;
  }
  if (i < 1024) {
    float d = 0.f, m = 0.f;
    for (int k = 0; k < 128; ++k) { d += hbd[k * 1024 + i]; m += hbm[k * 1024 + i]; }
    out[OUT_HBG + i] = m - d;
  }
  if (i == 0) {
    float s = 0.f;
    for (int k = 0; k < 256; ++k) s += recon_p[k];
    out[OUT_RECON] = s * (1.0f / 16777216.0f);  // /(B*V)
  }
}

extern "C" void kernel_launch(void* const* d_in, const int* in_sizes, int n_in,
                              void* d_out, int out_size, void* d_ws, size_t ws_size,
                              hipStream_t stream) {
  (void)in_sizes; (void)n_in; (void)out_size;
  const float* v   = (const float*)d_in[0];
  const float* w   = (const float*)d_in[1];
  const float* vb  = (const float*)d_in[2];
  const float* hb  = (const float*)d_in[3];
  const float* u_h = (const float*)d_in[4];
  const float* u_v = (const float*)d_in[5];
  float* out = (float*)d_out;
  char* ws = (char*)d_ws;
  if (ws_size < 204734464ULL) return;

  float* sums    = (float*)ws;               // 3.25 MiB region
  float* recon_p = sums;                     // 256
  float* vbd_p   = sums + 1024;              // 128*2048
  float* hbd_p   = vbd_p + 128 * 2048;       // 128*1024
  float* vbm_p   = hbd_p + 128 * 1024;       // 64*2048
  float* hbm_p   = vbm_p + 128 * 2048;       // 128*1024
  char* p = ws + 3407872;
  u16* v_cat  = (u16*)p;  p += (size_t)Bn * 2 * Vn * 2;   // 64 MiB [B,2V]
  u16* wT_cat = (u16*)p;  p += (size_t)Hn * 2 * Vn * 2;   // 8 MiB [H,2V]
  u16* w_cat  = (u16*)p;  p += (size_t)Vn * 2 * Hn * 2;   // 8 MiB [V,2H]
  u16* h_p    = (u16*)p;  p += BH * 2;                    // 16 MiB [B,H]
  u16* hbin   = (u16*)p;  p += BH * 2;                    // 16 MiB [B,H]
  u16* vT     = (u16*)p;  p += (size_t)Vn * Bn * 2;       // 32 MiB [V,B]
  u16* hT     = (u16*)p;  p += (size_t)Hn * Bn * 2;       // 16 MiB [H,B]
  float* big  = (float*)p;                                // 32 MiB time-shared
  u16* vk   = v_cat;            // v_cat dead after G1a
  u16* vkT  = vT;               // vT dead after G3
  u16* h2T  = hT;               // hT dead after G3
  float* vcat_f = (float*)v_cat;   // 64 MiB: G3's 8 partials (v_cat dead then)
  float* hpbuf  = (float*)h_p;     // h_p+hbin region (32 MiB) as f32 partials
  float* outW   = out + OUT_WGRAD;

  prep_vt_k<<<dim3(Bn / 64, Vn / 64), 256, 0, stream>>>(v, v_cat, vT, vbd_p);
  prep_w_k<<<dim3(Vn / 64, Hn / 64), 256, 0, stream>>>(w, w_cat, wT_cat);
  // G1a: split-K x2 partials (z0 -> out[0..BH) scratch, z1 -> big)
  gemm256<1><<<dim3(32, 4, 2), 512, 0, stream>>>(
      v_cat, 2 * Vn, wT_cat, 2 * Vn, 3072, nullptr, nullptr, nullptr,
      out, nullptr, nullptr, big, nullptr, nullptr);
  // epi: h_pred / h_p / hbin / hT / hbd
  epi_h_k<1><<<dim3(128, 16), 256, 0, stream>>>(
      out, big, hb, u_h, out, h_p, hbin, hT, hbd_p);
  // G2: recon partials (256 blocks)
  gemm256<2><<<dim3(32, 8), 512, 0, stream>>>(
      h_p, Hn, w_cat, 2 * Hn, Hn, vb, nullptr, v,
      nullptr, nullptr, nullptr, recon_p, nullptr, nullptr);
  // G3: w_data_grad partials (split-K x8 -> v_cat region, 64 MiB)
  gemm256<3><<<dim3(Vn / 256, Hn / 256, 8), 512, 0, stream>>>(
      vT, Bn, hT, Bn, 1024, nullptr, nullptr, nullptr,
      vcat_f, nullptr, nullptr, vcat_f + 4 * VH, nullptr, nullptr);
  reduce8_k<<<2048, 256, 0, stream>>>(vcat_f, outW);   // outW = data-grad sum
  // G4: vk/vkT + vbm partials (fused sample+transpose epilogue)
  gemm256<4><<<dim3(32, 8), 512, 0, stream>>>(
      hbin, Hn, w_cat, 2 * Hn, 2 * Hn, vb, u_v, nullptr,
      nullptr, vk, nullptr, nullptr, vkT, vbm_p);
  // G5a: split-K x2 partials (z0 -> hpbuf, z1 -> big); h_p/hbin dead now
  gemm256<5><<<dim3(32, 4, 2), 512, 0, stream>>>(
      vk, Vn, wT_cat, 2 * Vn, 2048, nullptr, nullptr, nullptr,
      hpbuf, nullptr, nullptr, big, nullptr, nullptr);
  // epi: h2T + hbm
  epi_h_k<5><<<dim3(128, 16), 256, 0, stream>>>(
      hpbuf, big, hb, u_h + BH, nullptr, nullptr, nullptr, h2T, hbm_p);
  // G6: w_model_grad partials (split-K x8: z<4 -> hpbuf, z>=4 -> big)
  gemm256<3><<<dim3(Vn / 256, Hn / 256, 8), 512, 0, stream>>>(
      vkT, Bn, h2T, Bn, 1024, nullptr, nullptr, nullptr,
      hpbuf, nullptr, nullptr, big, nullptr, nullptr);
  reduce8s_k<<<2048, 256, 0, stream>>>(hpbuf, big, outW, outW);  // model - data
  finalize_k<<<8, 256, 0, stream>>>(sums, out);
}